// Round 5
// baseline (99.126 us; speedup 1.0000x reference)
//
#include <hip/hip_runtime.h>
#include <math.h>

// Problem constants (from reference): B=65536, N=128, A=32, T=64
#define N_ATOMS  128
#define A_ALIGN  32
#define T_TRAIN  64
#define BPB      16           // batch rows per block (26 KB LDS -> 5-6 blocks/CU)
#define ROWF     (N_ATOMS*3)  // 384 floats per row
#define RPAD     388          // padded LDS row stride; lane stride 4 banks -> free 2-way alias

// One cyclic-Jacobi rotation on symmetric 3x3 Am, accumulating into Vm.
// Template indices keep all register-array indexing compile-time (no scratch).
template<int p, int q, int r>
__device__ __forceinline__ void jrot(float Am[3][3], float Vm[3][3])
{
    float apq = Am[p][q];
    float app = Am[p][p];
    float aqq = Am[q][q];
    float tau = (aqq - app) / (2.0f * apq);
    float tt  = 1.0f / (fabsf(tau) + sqrtf(1.0f + tau * tau));
    float t   = copysignf(tt, tau);
    t = (fabsf(apq) > 1e-20f) ? t : 0.0f;
    float c = 1.0f / sqrtf(1.0f + t * t);
    float s = t * c;
    float arp = Am[r][p], arq = Am[r][q];
    float nrp = c * arp - s * arq;
    float nrq = s * arp + c * arq;
    Am[r][p] = nrp; Am[p][r] = nrp;
    Am[r][q] = nrq; Am[q][r] = nrq;
    Am[p][p] = app - t * apq;
    Am[q][q] = aqq + t * apq;
    Am[p][q] = 0.0f; Am[q][p] = 0.0f;
#pragma unroll
    for (int k = 0; k < 3; ++k) {
        float vp = Vm[k][p], vq = Vm[k][q];
        Vm[k][p] = c * vp - s * vq;
        Vm[k][q] = s * vp + c * vq;
    }
}

__global__ __launch_bounds__(256, 5)
void kabsch_fused_kernel(const float* __restrict__ traj,
                         const float* __restrict__ ref_x,
                         const int*   __restrict__ align_idx,
                         const int*   __restrict__ train_idx,
                         float*       __restrict__ out,
                         int B)
{
    __shared__ float rowbuf[BPB * RPAD];     // 24832 B
    __shared__ float Rc[BPB][12];            // 768 B
    __shared__ float refb[A_ALIGN * 3];
    __shared__ int   idxa[A_ALIGN];
    __shared__ int   idxt[T_TRAIN];

    const int tid = threadIdx.x;
    const long long bbase = (long long)blockIdx.x * BPB;

    if (tid < A_ALIGN)     idxa[tid] = align_idx[tid];
    if (tid < T_TRAIN)     idxt[tid] = train_idx[tid];
    if (tid < A_ALIGN * 3) refb[tid] = ref_x[tid];

    // ---- stage: 16 rows = 6144 floats = 1536 float4, 6/thread, coalesced ----
    const float4* __restrict__ gsrc = (const float4*)(traj + bbase * ROWF);
    const long long f4max = ((long long)B * ROWF) / 4 - (bbase * ROWF) / 4;
#pragma unroll
    for (int k = 0; k < 6; ++k) {
        int f4 = tid + k * 256;
        if (f4 < f4max) {
            float4 v = gsrc[f4];
            int row = f4 / 96;              // 96 float4 per row
            int wi  = (f4 - row * 96) * 4;
            *(float4*)&rowbuf[row * RPAD + wi] = v;
        }
    }
    __syncthreads();

    // ---- Kabsch (Jacobi, proven): 16 lanes of wave (blockIdx&3), one row/lane.
    // kw spreads each block's serial chain across SIMDs.
    const int kw = blockIdx.x & 3;
    if ((tid >> 6) == kw && (tid & 63) < BPB && (bbase + (tid & 63)) < B) {
        const int l = tid & 63;
        const float* __restrict__ row = &rowbuf[l * RPAD];

        float S00=0,S01=0,S02=0,S10=0,S11=0,S12=0,S20=0,S21=0,S22=0;
        float xs0=0,xs1=0,xs2=0, rs0=0,rs1=0,rs2=0;
#pragma unroll
        for (int a = 0; a < A_ALIGN; ++a) {
            int ia = idxa[a];                    // uniform -> broadcast
            float px = row[ia*3+0], py = row[ia*3+1], pz = row[ia*3+2];
            float rx = refb[a*3+0], ry = refb[a*3+1], rz = refb[a*3+2];
            S00 += px*rx; S01 += px*ry; S02 += px*rz;
            S10 += py*rx; S11 += py*ry; S12 += py*rz;
            S20 += pz*rx; S21 += pz*ry; S22 += pz*rz;
            xs0 += px; xs1 += py; xs2 += pz;
            rs0 += rx; rs1 += ry; rs2 += rz;
        }
        const float inv_a = 1.0f / (float)A_ALIGN;
        float c0 = xs0*inv_a, c1 = xs1*inv_a, c2 = xs2*inv_a;
        float P00 = S00 - c0*rs0, P01 = S01 - c0*rs1, P02 = S02 - c0*rs2;
        float P10 = S10 - c1*rs0, P11 = S11 - c1*rs1, P12 = S12 - c1*rs2;
        float P20 = S20 - c2*rs0, P21 = S21 - c2*rs1, P22 = S22 - c2*rs2;

        float Am[3][3], Vm[3][3];
        Am[0][0] = P00*P00 + P10*P10 + P20*P20;
        Am[0][1] = P00*P01 + P10*P11 + P20*P21;
        Am[0][2] = P00*P02 + P10*P12 + P20*P22;
        Am[1][1] = P01*P01 + P11*P11 + P21*P21;
        Am[1][2] = P01*P02 + P11*P12 + P21*P22;
        Am[2][2] = P02*P02 + P12*P12 + P22*P22;
        Am[1][0]=Am[0][1]; Am[2][0]=Am[0][2]; Am[2][1]=Am[1][2];
        Vm[0][0]=1.f; Vm[0][1]=0.f; Vm[0][2]=0.f;
        Vm[1][0]=0.f; Vm[1][1]=1.f; Vm[1][2]=0.f;
        Vm[2][0]=0.f; Vm[2][1]=0.f; Vm[2][2]=1.f;
#pragma unroll
        for (int sw = 0; sw < 6; ++sw) {
            jrot<0,1,2>(Am, Vm);
            jrot<0,2,1>(Am, Vm);
            jrot<1,2,0>(Am, Vm);
        }

        float l0 = Am[0][0], l1 = Am[1][1], l2 = Am[2][2];
        float v0x=Vm[0][0], v0y=Vm[1][0], v0z=Vm[2][0];
        float v1x=Vm[0][1], v1y=Vm[1][1], v1z=Vm[2][1];
        if (l0 < l1) { float t; t=l0;l0=l1;l1=t;
                       t=v0x;v0x=v1x;v1x=t; t=v0y;v0y=v1y;v1y=t; t=v0z;v0z=v1z;v1z=t; }
        { float v2x=Vm[0][2], v2y=Vm[1][2], v2z=Vm[2][2];
          if (l0 < l2) { float t; t=l0;l0=l2;l2=t;
                         t=v0x;v0x=v2x;v2x=t; t=v0y;v0y=v2y;v2y=t; t=v0z;v0z=v2z;v2z=t; }
          if (l1 < l2) { float t; t=l1;l1=l2;l2=t;
                         t=v1x;v1x=v2x;v2x=t; t=v1y;v1y=v2y;v2y=t; t=v1z;v1z=v2z;v2z=t; }
        }
        float v2x = v0y*v1z - v0z*v1y;
        float v2y = v0z*v1x - v0x*v1z;
        float v2z = v0x*v1y - v0y*v1x;
        float w0x = P00*v0x + P01*v0y + P02*v0z;
        float w0y = P10*v0x + P11*v0y + P12*v0z;
        float w0z = P20*v0x + P21*v0y + P22*v0z;
        float i0 = 1.0f / sqrtf(fmaxf(w0x*w0x+w0y*w0y+w0z*w0z, 1e-30f));
        float u0x=w0x*i0, u0y=w0y*i0, u0z=w0z*i0;
        float w1x = P00*v1x + P01*v1y + P02*v1z;
        float w1y = P10*v1x + P11*v1y + P12*v1z;
        float w1z = P20*v1x + P21*v1y + P22*v1z;
        float d01 = u0x*w1x + u0y*w1y + u0z*w1z;
        w1x -= d01*u0x; w1y -= d01*u0y; w1z -= d01*u0z;
        float i1 = 1.0f / sqrtf(fmaxf(w1x*w1x+w1y*w1y+w1z*w1z, 1e-30f));
        float u1x=w1x*i1, u1y=w1y*i1, u1z=w1z*i1;
        float u2x = u0y*u1z - u0z*u1y;
        float u2y = u0z*u1x - u0x*u1z;
        float u2z = u0x*u1y - u0y*u1x;

        // R = U~ V~^T (row-major); transform applies y = x . R
        Rc[l][0] = u0x*v0x + u1x*v1x + u2x*v2x;
        Rc[l][1] = u0x*v0y + u1x*v1y + u2x*v2y;
        Rc[l][2] = u0x*v0z + u1x*v1z + u2x*v2z;
        Rc[l][3] = u0y*v0x + u1y*v1x + u2y*v2x;
        Rc[l][4] = u0y*v0y + u1y*v1y + u2y*v2y;
        Rc[l][5] = u0y*v0z + u1y*v1z + u2y*v2z;
        Rc[l][6] = u0z*v0x + u1z*v1x + u2z*v2x;
        Rc[l][7] = u0z*v0y + u1z*v1y + u2z*v2y;
        Rc[l][8] = u0z*v0z + u1z*v1z + u2z*v2z;
        Rc[l][9]  = c0;
        Rc[l][10] = c1;
        Rc[l][11] = c2;
    }
    __syncthreads();

    // ---- transform: 16 rows x 64 train atoms = 1024 outputs, 4/thread ----
#pragma unroll
    for (int k = 0; k < 4; ++k) {
        int a = tid + k * 256;
        int r = a >> 6;
        int t = a & 63;
        if (bbase + r >= B) break;
        int ti = idxt[t];
        const float* __restrict__ rb = &rowbuf[r * RPAD];
        float c0 = Rc[r][9], c1 = Rc[r][10], c2 = Rc[r][11];
        float x0 = rb[ti*3+0]-c0, x1 = rb[ti*3+1]-c1, x2 = rb[ti*3+2]-c2;
        float y0 = x0*Rc[r][0] + x1*Rc[r][3] + x2*Rc[r][6];
        float y1 = x0*Rc[r][1] + x1*Rc[r][4] + x2*Rc[r][7];
        float y2 = x0*Rc[r][2] + x1*Rc[r][5] + x2*Rc[r][8];
        float* o = out + ((bbase + r) * T_TRAIN + t) * 3;
        o[0]=y0; o[1]=y1; o[2]=y2;
    }
}

extern "C" void kernel_launch(void* const* d_in, const int* in_sizes, int n_in,
                              void* d_out, int out_size, void* d_ws, size_t ws_size,
                              hipStream_t stream)
{
    const float* traj      = (const float*)d_in[0];
    const float* ref_x     = (const float*)d_in[1];
    const int*   align_idx = (const int*)d_in[2];
    const int*   train_idx = (const int*)d_in[3];
    float* out = (float*)d_out;
    int B = in_sizes[0] / (N_ATOMS * 3);

    int nblk = (B + BPB - 1) / BPB;
    kabsch_fused_kernel<<<dim3(nblk), dim3(256), 0, stream>>>(
        traj, ref_x, align_idx, train_idx, out, B);
}

// Round 6
// 71.071 us; speedup vs baseline: 1.3948x; 1.3948x over previous
//
#include <hip/hip_runtime.h>
#include <math.h>

// Problem constants (from reference): B=65536, N=128, A=32, T=64
#define N_ATOMS  128
#define A_ALIGN  32
#define T_TRAIN  64
#define BPB      16           // batch rows per block
#define ROWF     (N_ATOMS*3)  // 384 floats per row
#define RPAD     388          // padded LDS row stride
#define OROW     (T_TRAIN*3)  // 192 floats out per row

// One cyclic-Jacobi rotation on symmetric 3x3 Am, accumulating into Vm.
template<int p, int q, int r>
__device__ __forceinline__ void jrot(float Am[3][3], float Vm[3][3])
{
    float apq = Am[p][q];
    float app = Am[p][p];
    float aqq = Am[q][q];
    float tau = (aqq - app) / (2.0f * apq);
    float tt  = 1.0f / (fabsf(tau) + sqrtf(1.0f + tau * tau));
    float t   = copysignf(tt, tau);
    t = (fabsf(apq) > 1e-20f) ? t : 0.0f;
    float c = 1.0f / sqrtf(1.0f + t * t);
    float s = t * c;
    float arp = Am[r][p], arq = Am[r][q];
    float nrp = c * arp - s * arq;
    float nrq = s * arp + c * arq;
    Am[r][p] = nrp; Am[p][r] = nrp;
    Am[r][q] = nrq; Am[q][r] = nrq;
    Am[p][p] = app - t * apq;
    Am[q][q] = aqq + t * apq;
    Am[p][q] = 0.0f; Am[q][p] = 0.0f;
#pragma unroll
    for (int k = 0; k < 3; ++k) {
        float vp = Vm[k][p], vq = Vm[k][q];
        Vm[k][p] = c * vp - s * vq;
        Vm[k][q] = s * vp + c * vq;
    }
}

__global__ __launch_bounds__(256, 4)
void kabsch_fused_kernel(const float* __restrict__ traj,
                         const float* __restrict__ ref_x,
                         const int*   __restrict__ align_idx,
                         const int*   __restrict__ train_idx,
                         float*       __restrict__ out,
                         int B)
{
    __shared__ float rowbuf[BPB * RPAD];     // 24832 B
    __shared__ float obuf[BPB * OROW];       // 12288 B  (dense out staging)
    __shared__ float Rc[BPB][12];            // 768 B
    __shared__ float refb[A_ALIGN * 3];
    __shared__ int   idxa[A_ALIGN];
    __shared__ int   idxt[T_TRAIN];

    const int tid = threadIdx.x;
    const long long bbase = (long long)blockIdx.x * BPB;

    if (tid < A_ALIGN)     idxa[tid] = align_idx[tid];
    if (tid < T_TRAIN)     idxt[tid] = train_idx[tid];
    if (tid < A_ALIGN * 3) refb[tid] = ref_x[tid];

    // ---- stage: 16 rows = 1536 float4, 6/thread, coalesced ----
    const float4* __restrict__ gsrc = (const float4*)(traj + bbase * ROWF);
    const long long f4max = ((long long)B * ROWF) / 4 - (bbase * ROWF) / 4;
#pragma unroll
    for (int k = 0; k < 6; ++k) {
        int f4 = tid + k * 256;
        if (f4 < f4max) {
            float4 v = gsrc[f4];
            int row = f4 / 96;              // 96 float4 per row
            int wi  = (f4 - row * 96) * 4;
            *(float4*)&rowbuf[row * RPAD + wi] = v;
        }
    }
    __syncthreads();

    // ---- Kabsch (Jacobi): 16 lanes of wave (blockIdx&3), one row/lane ----
    const int kw = blockIdx.x & 3;
    if ((tid >> 6) == kw && (tid & 63) < BPB && (bbase + (tid & 63)) < B) {
        const int l = tid & 63;
        const float* __restrict__ row = &rowbuf[l * RPAD];

        float S00=0,S01=0,S02=0,S10=0,S11=0,S12=0,S20=0,S21=0,S22=0;
        float xs0=0,xs1=0,xs2=0, rs0=0,rs1=0,rs2=0;
#pragma unroll
        for (int a = 0; a < A_ALIGN; ++a) {
            int ia = idxa[a];                    // uniform -> broadcast
            float px = row[ia*3+0], py = row[ia*3+1], pz = row[ia*3+2];
            float rx = refb[a*3+0], ry = refb[a*3+1], rz = refb[a*3+2];
            S00 += px*rx; S01 += px*ry; S02 += px*rz;
            S10 += py*rx; S11 += py*ry; S12 += py*rz;
            S20 += pz*rx; S21 += pz*ry; S22 += pz*rz;
            xs0 += px; xs1 += py; xs2 += pz;
            rs0 += rx; rs1 += ry; rs2 += rz;
        }
        const float inv_a = 1.0f / (float)A_ALIGN;
        float c0 = xs0*inv_a, c1 = xs1*inv_a, c2 = xs2*inv_a;
        float P00 = S00 - c0*rs0, P01 = S01 - c0*rs1, P02 = S02 - c0*rs2;
        float P10 = S10 - c1*rs0, P11 = S11 - c1*rs1, P12 = S12 - c1*rs2;
        float P20 = S20 - c2*rs0, P21 = S21 - c2*rs1, P22 = S22 - c2*rs2;

        float Am[3][3], Vm[3][3];
        Am[0][0] = P00*P00 + P10*P10 + P20*P20;
        Am[0][1] = P00*P01 + P10*P11 + P20*P21;
        Am[0][2] = P00*P02 + P10*P12 + P20*P22;
        Am[1][1] = P01*P01 + P11*P11 + P21*P21;
        Am[1][2] = P01*P02 + P11*P12 + P21*P22;
        Am[2][2] = P02*P02 + P12*P12 + P22*P22;
        Am[1][0]=Am[0][1]; Am[2][0]=Am[0][2]; Am[2][1]=Am[1][2];
        Vm[0][0]=1.f; Vm[0][1]=0.f; Vm[0][2]=0.f;
        Vm[1][0]=0.f; Vm[1][1]=1.f; Vm[1][2]=0.f;
        Vm[2][0]=0.f; Vm[2][1]=0.f; Vm[2][2]=1.f;
#pragma unroll
        for (int sw = 0; sw < 6; ++sw) {
            jrot<0,1,2>(Am, Vm);
            jrot<0,2,1>(Am, Vm);
            jrot<1,2,0>(Am, Vm);
        }

        float l0 = Am[0][0], l1 = Am[1][1], l2 = Am[2][2];
        float v0x=Vm[0][0], v0y=Vm[1][0], v0z=Vm[2][0];
        float v1x=Vm[0][1], v1y=Vm[1][1], v1z=Vm[2][1];
        if (l0 < l1) { float t; t=l0;l0=l1;l1=t;
                       t=v0x;v0x=v1x;v1x=t; t=v0y;v0y=v1y;v1y=t; t=v0z;v0z=v1z;v1z=t; }
        { float v2x=Vm[0][2], v2y=Vm[1][2], v2z=Vm[2][2];
          if (l0 < l2) { float t; t=l0;l0=l2;l2=t;
                         t=v0x;v0x=v2x;v2x=t; t=v0y;v0y=v2y;v2y=t; t=v0z;v0z=v2z;v2z=t; }
          if (l1 < l2) { float t; t=l1;l1=l2;l2=t;
                         t=v1x;v1x=v2x;v2x=t; t=v1y;v1y=v2y;v2y=t; t=v1z;v1z=v2z;v2z=t; }
        }
        float v2x = v0y*v1z - v0z*v1y;
        float v2y = v0z*v1x - v0x*v1z;
        float v2z = v0x*v1y - v0y*v1x;
        float w0x = P00*v0x + P01*v0y + P02*v0z;
        float w0y = P10*v0x + P11*v0y + P12*v0z;
        float w0z = P20*v0x + P21*v0y + P22*v0z;
        float i0 = 1.0f / sqrtf(fmaxf(w0x*w0x+w0y*w0y+w0z*w0z, 1e-30f));
        float u0x=w0x*i0, u0y=w0y*i0, u0z=w0z*i0;
        float w1x = P00*v1x + P01*v1y + P02*v1z;
        float w1y = P10*v1x + P11*v1y + P12*v1z;
        float w1z = P20*v1x + P21*v1y + P22*v1z;
        float d01 = u0x*w1x + u0y*w1y + u0z*w1z;
        w1x -= d01*u0x; w1y -= d01*u0y; w1z -= d01*u0z;
        float i1 = 1.0f / sqrtf(fmaxf(w1x*w1x+w1y*w1y+w1z*w1z, 1e-30f));
        float u1x=w1x*i1, u1y=w1y*i1, u1z=w1z*i1;
        float u2x = u0y*u1z - u0z*u1y;
        float u2y = u0z*u1x - u0x*u1z;
        float u2z = u0x*u1y - u0y*u1x;

        Rc[l][0] = u0x*v0x + u1x*v1x + u2x*v2x;
        Rc[l][1] = u0x*v0y + u1x*v1y + u2x*v2y;
        Rc[l][2] = u0x*v0z + u1x*v1z + u2x*v2z;
        Rc[l][3] = u0y*v0x + u1y*v1x + u2y*v2x;
        Rc[l][4] = u0y*v0y + u1y*v1y + u2y*v2y;
        Rc[l][5] = u0y*v0z + u1y*v1z + u2y*v2z;
        Rc[l][6] = u0z*v0x + u1z*v1x + u2z*v2x;
        Rc[l][7] = u0z*v0y + u1z*v1y + u2z*v2y;
        Rc[l][8] = u0z*v0z + u1z*v1z + u2z*v2z;
        Rc[l][9]  = c0;
        Rc[l][10] = c1;
        Rc[l][11] = c2;
    }
    __syncthreads();

    // ---- transform into LDS out-staging (dense writes later) ----
#pragma unroll
    for (int k = 0; k < 4; ++k) {
        int a = tid + k * 256;
        int r = a >> 6;
        int t = a & 63;
        int ti = idxt[t];
        const float* __restrict__ rb = &rowbuf[r * RPAD];
        float c0 = Rc[r][9], c1 = Rc[r][10], c2 = Rc[r][11];
        float x0 = rb[ti*3+0]-c0, x1 = rb[ti*3+1]-c1, x2 = rb[ti*3+2]-c2;
        // stride-3 LDS write: conflict-free within 32 lanes (gcd(3,32)=1),
        // 2-way alias across half-wave = free
        float* ob = &obuf[r * OROW + t * 3];
        ob[0] = x0*Rc[r][0] + x1*Rc[r][3] + x2*Rc[r][6];
        ob[1] = x0*Rc[r][1] + x1*Rc[r][4] + x2*Rc[r][7];
        ob[2] = x0*Rc[r][2] + x1*Rc[r][5] + x2*Rc[r][8];
    }
    __syncthreads();

    // ---- dense cooperative writeback: 3072 floats = 768 float4, 3/thread ----
    float4* __restrict__ gdst = (float4*)(out + bbase * OROW);
    const long long o4max = ((long long)B * OROW) / 4 - (bbase * OROW) / 4;
#pragma unroll
    for (int k = 0; k < 3; ++k) {
        int f4 = tid + k * 256;
        if (f4 < o4max)
            gdst[f4] = *(const float4*)&obuf[f4 * 4];
    }
}

extern "C" void kernel_launch(void* const* d_in, const int* in_sizes, int n_in,
                              void* d_out, int out_size, void* d_ws, size_t ws_size,
                              hipStream_t stream)
{
    const float* traj      = (const float*)d_in[0];
    const float* ref_x     = (const float*)d_in[1];
    const int*   align_idx = (const int*)d_in[2];
    const int*   train_idx = (const int*)d_in[3];
    float* out = (float*)d_out;
    int B = in_sizes[0] / (N_ATOMS * 3);

    int nblk = (B + BPB - 1) / BPB;
    kabsch_fused_kernel<<<dim3(nblk), dim3(256), 0, stream>>>(
        traj, ref_x, align_idx, train_idx, out, B);
}

// Round 7
// 70.542 us; speedup vs baseline: 1.4052x; 1.0075x over previous
//
#include <hip/hip_runtime.h>
#include <math.h>

// Problem constants (from reference): B=65536, N=128, A=32, T=64
#define N_ATOMS  128
#define A_ALIGN  32
#define T_TRAIN  64
#define BPB      16           // rows per tile
#define ROWF     (N_ATOMS*3)  // 384 floats per row
#define R4       (ROWF/4)     // 96 float4 per row
#define RPAD     388          // padded LDS row stride (floats)
#define GRID_MAX 768          // 3 blocks/CU x 256 CU

// One cyclic-Jacobi rotation on symmetric 3x3 Am, accumulating into Vm.
template<int p, int q, int r>
__device__ __forceinline__ void jrot(float Am[3][3], float Vm[3][3])
{
    float apq = Am[p][q];
    float app = Am[p][p];
    float aqq = Am[q][q];
    float tau = (aqq - app) / (2.0f * apq);
    float tt  = 1.0f / (fabsf(tau) + sqrtf(1.0f + tau * tau));
    float t   = copysignf(tt, tau);
    t = (fabsf(apq) > 1e-20f) ? t : 0.0f;
    float c = 1.0f / sqrtf(1.0f + t * t);
    float s = t * c;
    float arp = Am[r][p], arq = Am[r][q];
    float nrp = c * arp - s * arq;
    float nrq = s * arp + c * arq;
    Am[r][p] = nrp; Am[p][r] = nrp;
    Am[r][q] = nrq; Am[q][r] = nrq;
    Am[p][p] = app - t * apq;
    Am[q][q] = aqq + t * apq;
    Am[p][q] = 0.0f; Am[q][p] = 0.0f;
#pragma unroll
    for (int k = 0; k < 3; ++k) {
        float vp = Vm[k][p], vq = Vm[k][q];
        Vm[k][p] = c * vp - s * vq;
        Vm[k][q] = s * vp + c * vq;
    }
}

// Persistent double-buffered pipeline:
//   top barrier -> issue next-tile global loads (regs) -> Kabsch (1 rotating
//   wave) -> mid barrier -> transform + direct stores -> ds_write prefetch.
__global__ __launch_bounds__(256, 3)
void kabsch_pipe_kernel(const float* __restrict__ traj,
                        const float* __restrict__ ref_x,
                        const int*   __restrict__ align_idx,
                        const int*   __restrict__ train_idx,
                        float*       __restrict__ out,
                        int B, int ntiles)
{
    __shared__ float rowbuf[2][BPB * RPAD];  // 49664 B
    __shared__ float Rc[BPB][12];
    __shared__ float refb[A_ALIGN * 3];
    __shared__ int   idxa[A_ALIGN];
    __shared__ int   idxt[T_TRAIN];

    const int tid = threadIdx.x;
    if (tid < A_ALIGN)     idxa[tid] = align_idx[tid];
    if (tid < T_TRAIN)     idxt[tid] = train_idx[tid];
    if (tid < A_ALIGN * 3) refb[tid] = ref_x[tid];

    const long long totf4 = (long long)B * R4;
    const float4* __restrict__ gsrc = (const float4*)traj;

    // ---- prologue: stage first tile into buf 0 ----
    int tile = blockIdx.x;
    {
        long long base = (long long)tile * (BPB * R4);
#pragma unroll
        for (int k = 0; k < 6; ++k) {
            long long f4 = base + tid + k * 256;
            if (f4 < totf4) {
                float4 v = gsrc[f4];
                int loc = tid + k * 256;
                int row = loc / R4;
                int wi  = (loc - row * R4) * 4;
                *(float4*)&rowbuf[0][row * RPAD + wi] = v;
            }
        }
    }

    int c  = 0;
    int it = 0;
    for (; tile < ntiles; tile += gridDim.x, ++it) {
        __syncthreads();   // buf[c] visible; prev iter's readers of buf[c^1] done

        // ---- issue next tile's loads into registers (write to LDS later) ----
        const int nt = tile + (int)gridDim.x;
        float4 pf0, pf1, pf2, pf3, pf4, pf5;
        bool   pv0, pv1, pv2, pv3, pv4, pv5;
        {
            long long nbase = (long long)nt * (BPB * R4);
            long long f4;
            f4 = nbase + tid + 0*256; pv0 = (nt < ntiles) && (f4 < totf4); if (pv0) pf0 = gsrc[f4];
            f4 = nbase + tid + 1*256; pv1 = (nt < ntiles) && (f4 < totf4); if (pv1) pf1 = gsrc[f4];
            f4 = nbase + tid + 2*256; pv2 = (nt < ntiles) && (f4 < totf4); if (pv2) pf2 = gsrc[f4];
            f4 = nbase + tid + 3*256; pv3 = (nt < ntiles) && (f4 < totf4); if (pv3) pf3 = gsrc[f4];
            f4 = nbase + tid + 4*256; pv4 = (nt < ntiles) && (f4 < totf4); if (pv4) pf4 = gsrc[f4];
            f4 = nbase + tid + 5*256; pv5 = (nt < ntiles) && (f4 < totf4); if (pv5) pf5 = gsrc[f4];
        }

        const long long bbase = (long long)tile * BPB;

        // ---- Kabsch (Jacobi): 16 lanes of rotating wave, one row/lane ----
        const int w = (it + (int)blockIdx.x) & 3;
        if ((tid >> 6) == w && (tid & 63) < BPB && (bbase + (tid & 63)) < B) {
            const int l = tid & 63;
            const float* __restrict__ row = &rowbuf[c][l * RPAD];

            float S00=0,S01=0,S02=0,S10=0,S11=0,S12=0,S20=0,S21=0,S22=0;
            float xs0=0,xs1=0,xs2=0, rs0=0,rs1=0,rs2=0;
#pragma unroll
            for (int a = 0; a < A_ALIGN; ++a) {
                int ia = idxa[a];                    // uniform -> broadcast
                float px = row[ia*3+0], py = row[ia*3+1], pz = row[ia*3+2];
                float rx = refb[a*3+0], ry = refb[a*3+1], rz = refb[a*3+2];
                S00 += px*rx; S01 += px*ry; S02 += px*rz;
                S10 += py*rx; S11 += py*ry; S12 += py*rz;
                S20 += pz*rx; S21 += pz*ry; S22 += pz*rz;
                xs0 += px; xs1 += py; xs2 += pz;
                rs0 += rx; rs1 += ry; rs2 += rz;
            }
            const float inv_a = 1.0f / (float)A_ALIGN;
            float c0 = xs0*inv_a, c1 = xs1*inv_a, c2 = xs2*inv_a;
            float P00 = S00 - c0*rs0, P01 = S01 - c0*rs1, P02 = S02 - c0*rs2;
            float P10 = S10 - c1*rs0, P11 = S11 - c1*rs1, P12 = S12 - c1*rs2;
            float P20 = S20 - c2*rs0, P21 = S21 - c2*rs1, P22 = S22 - c2*rs2;

            float Am[3][3], Vm[3][3];
            Am[0][0] = P00*P00 + P10*P10 + P20*P20;
            Am[0][1] = P00*P01 + P10*P11 + P20*P21;
            Am[0][2] = P00*P02 + P10*P12 + P20*P22;
            Am[1][1] = P01*P01 + P11*P11 + P21*P21;
            Am[1][2] = P01*P02 + P11*P12 + P21*P22;
            Am[2][2] = P02*P02 + P12*P12 + P22*P22;
            Am[1][0]=Am[0][1]; Am[2][0]=Am[0][2]; Am[2][1]=Am[1][2];
            Vm[0][0]=1.f; Vm[0][1]=0.f; Vm[0][2]=0.f;
            Vm[1][0]=0.f; Vm[1][1]=1.f; Vm[1][2]=0.f;
            Vm[2][0]=0.f; Vm[2][1]=0.f; Vm[2][2]=1.f;
#pragma unroll
            for (int sw = 0; sw < 6; ++sw) {
                jrot<0,1,2>(Am, Vm);
                jrot<0,2,1>(Am, Vm);
                jrot<1,2,0>(Am, Vm);
            }

            float l0 = Am[0][0], l1 = Am[1][1], l2 = Am[2][2];
            float v0x=Vm[0][0], v0y=Vm[1][0], v0z=Vm[2][0];
            float v1x=Vm[0][1], v1y=Vm[1][1], v1z=Vm[2][1];
            if (l0 < l1) { float t; t=l0;l0=l1;l1=t;
                           t=v0x;v0x=v1x;v1x=t; t=v0y;v0y=v1y;v1y=t; t=v0z;v0z=v1z;v1z=t; }
            { float v2x=Vm[0][2], v2y=Vm[1][2], v2z=Vm[2][2];
              if (l0 < l2) { float t; t=l0;l0=l2;l2=t;
                             t=v0x;v0x=v2x;v2x=t; t=v0y;v0y=v2y;v2y=t; t=v0z;v0z=v2z;v2z=t; }
              if (l1 < l2) { float t; t=l1;l1=l2;l2=t;
                             t=v1x;v1x=v2x;v2x=t; t=v1y;v1y=v2y;v2y=t; t=v1z;v1z=v2z;v2z=t; }
            }
            float v2x = v0y*v1z - v0z*v1y;
            float v2y = v0z*v1x - v0x*v1z;
            float v2z = v0x*v1y - v0y*v1x;
            float w0x = P00*v0x + P01*v0y + P02*v0z;
            float w0y = P10*v0x + P11*v0y + P12*v0z;
            float w0z = P20*v0x + P21*v0y + P22*v0z;
            float i0 = 1.0f / sqrtf(fmaxf(w0x*w0x+w0y*w0y+w0z*w0z, 1e-30f));
            float u0x=w0x*i0, u0y=w0y*i0, u0z=w0z*i0;
            float w1x = P00*v1x + P01*v1y + P02*v1z;
            float w1y = P10*v1x + P11*v1y + P12*v1z;
            float w1z = P20*v1x + P21*v1y + P22*v1z;
            float d01 = u0x*w1x + u0y*w1y + u0z*w1z;
            w1x -= d01*u0x; w1y -= d01*u0y; w1z -= d01*u0z;
            float i1 = 1.0f / sqrtf(fmaxf(w1x*w1x+w1y*w1y+w1z*w1z, 1e-30f));
            float u1x=w1x*i1, u1y=w1y*i1, u1z=w1z*i1;
            float u2x = u0y*u1z - u0z*u1y;
            float u2y = u0z*u1x - u0x*u1z;
            float u2z = u0x*u1y - u0y*u1x;

            Rc[l][0] = u0x*v0x + u1x*v1x + u2x*v2x;
            Rc[l][1] = u0x*v0y + u1x*v1y + u2x*v2y;
            Rc[l][2] = u0x*v0z + u1x*v1z + u2x*v2z;
            Rc[l][3] = u0y*v0x + u1y*v1x + u2y*v2x;
            Rc[l][4] = u0y*v0y + u1y*v1y + u2y*v2y;
            Rc[l][5] = u0y*v0z + u1y*v1z + u2y*v2z;
            Rc[l][6] = u0z*v0x + u1z*v1x + u2z*v2x;
            Rc[l][7] = u0z*v0y + u1z*v1y + u2z*v2y;
            Rc[l][8] = u0z*v0z + u1z*v1z + u2z*v2z;
            Rc[l][9]  = c0;
            Rc[l][10] = c1;
            Rc[l][11] = c2;
        }
        __syncthreads();   // Rc ready

        // ---- transform: 16 rows x 64 train atoms, direct stride-3 stores ----
#pragma unroll
        for (int k = 0; k < 4; ++k) {
            int a = tid + k * 256;
            int r = a >> 6;
            int t = a & 63;
            if (bbase + r < B) {
                int ti = idxt[t];
                const float* __restrict__ rb = &rowbuf[c][r * RPAD];
                float c0 = Rc[r][9], c1 = Rc[r][10], c2 = Rc[r][11];
                float x0 = rb[ti*3+0]-c0, x1 = rb[ti*3+1]-c1, x2 = rb[ti*3+2]-c2;
                float y0 = x0*Rc[r][0] + x1*Rc[r][3] + x2*Rc[r][6];
                float y1 = x0*Rc[r][1] + x1*Rc[r][4] + x2*Rc[r][7];
                float y2 = x0*Rc[r][2] + x1*Rc[r][5] + x2*Rc[r][8];
                float* o = out + ((bbase + r) * T_TRAIN + t) * 3;
                o[0]=y0; o[1]=y1; o[2]=y2;
            }
        }

        // ---- write prefetched tile into the other buffer (latency hidden) ----
        {
            int loc, row, wi;
            if (pv0) { loc = tid + 0*256; row = loc / R4; wi = (loc - row*R4)*4; *(float4*)&rowbuf[c^1][row*RPAD+wi] = pf0; }
            if (pv1) { loc = tid + 1*256; row = loc / R4; wi = (loc - row*R4)*4; *(float4*)&rowbuf[c^1][row*RPAD+wi] = pf1; }
            if (pv2) { loc = tid + 2*256; row = loc / R4; wi = (loc - row*R4)*4; *(float4*)&rowbuf[c^1][row*RPAD+wi] = pf2; }
            if (pv3) { loc = tid + 3*256; row = loc / R4; wi = (loc - row*R4)*4; *(float4*)&rowbuf[c^1][row*RPAD+wi] = pf3; }
            if (pv4) { loc = tid + 4*256; row = loc / R4; wi = (loc - row*R4)*4; *(float4*)&rowbuf[c^1][row*RPAD+wi] = pf4; }
            if (pv5) { loc = tid + 5*256; row = loc / R4; wi = (loc - row*R4)*4; *(float4*)&rowbuf[c^1][row*RPAD+wi] = pf5; }
        }
        c ^= 1;
    }
}

extern "C" void kernel_launch(void* const* d_in, const int* in_sizes, int n_in,
                              void* d_out, int out_size, void* d_ws, size_t ws_size,
                              hipStream_t stream)
{
    const float* traj      = (const float*)d_in[0];
    const float* ref_x     = (const float*)d_in[1];
    const int*   align_idx = (const int*)d_in[2];
    const int*   train_idx = (const int*)d_in[3];
    float* out = (float*)d_out;
    int B = in_sizes[0] / (N_ATOMS * 3);

    int ntiles = (B + BPB - 1) / BPB;
    int grid = ntiles < GRID_MAX ? ntiles : GRID_MAX;
    kabsch_pipe_kernel<<<dim3(grid), dim3(256), 0, stream>>>(
        traj, ref_x, align_idx, train_idx, out, B, ntiles);
}

// Round 8
// 51.851 us; speedup vs baseline: 1.9117x; 1.3605x over previous
//
#include <hip/hip_runtime.h>
#include <math.h>

// Problem constants (from reference): B=65536, N=128, A=32, T=64
#define N_ATOMS  128
#define A_ALIGN  32
#define T_TRAIN  64
#define ROWF     (N_ATOMS*3)   // 384 floats per row
#define R4       (ROWF/4)      // 96 float4 per row

// One cyclic-Jacobi rotation on symmetric 3x3 Am, accumulating into Vm.
template<int p, int q, int r>
__device__ __forceinline__ void jrot(float Am[3][3], float Vm[3][3])
{
    float apq = Am[p][q];
    float app = Am[p][p];
    float aqq = Am[q][q];
    float tau = (aqq - app) / (2.0f * apq);
    float tt  = 1.0f / (fabsf(tau) + sqrtf(1.0f + tau * tau));
    float t   = copysignf(tt, tau);
    t = (fabsf(apq) > 1e-20f) ? t : 0.0f;
    float c = 1.0f / sqrtf(1.0f + t * t);
    float s = t * c;
    float arp = Am[r][p], arq = Am[r][q];
    float nrp = c * arp - s * arq;
    float nrq = s * arp + c * arq;
    Am[r][p] = nrp; Am[p][r] = nrp;
    Am[r][q] = nrq; Am[q][r] = nrq;
    Am[p][p] = app - t * apq;
    Am[q][q] = aqq + t * apq;
    Am[p][q] = 0.0f; Am[q][p] = 0.0f;
#pragma unroll
    for (int k = 0; k < 3; ++k) {
        float vp = Vm[k][p], vq = Vm[k][q];
        Vm[k][p] = c * vp - s * vq;
        Vm[k][q] = s * vp + c * vq;
    }
}

// K1: one thread per batch row. 64 independent Kabsch chains per wave ->
// latency hidden by lane-parallelism, total work only ~1024 waves.
// Writes R (row-major) + centroid as AoS rws[b*12 + k], 3x float4 per thread.
template<bool FUSED>
__global__ __launch_bounds__(64)
void kabsch_rot_kernel(const float* __restrict__ traj,
                       const float* __restrict__ ref_x,
                       const int*   __restrict__ align_idx,
                       const int*   __restrict__ train_idx,
                       float*       __restrict__ rws,
                       float*       __restrict__ out,
                       int B)
{
    int b = blockIdx.x * 64 + threadIdx.x;
    if (b >= B) return;
    const float* __restrict__ row = traj + (size_t)b * ROWF;

    float S00=0,S01=0,S02=0,S10=0,S11=0,S12=0,S20=0,S21=0,S22=0;
    float xs0=0,xs1=0,xs2=0, rs0=0,rs1=0,rs2=0;
#pragma unroll
    for (int a = 0; a < A_ALIGN; ++a) {
        int ia = align_idx[a];                    // uniform -> scalar load
        float px = row[ia*3+0], py = row[ia*3+1], pz = row[ia*3+2];
        float rx = ref_x[a*3+0], ry = ref_x[a*3+1], rz = ref_x[a*3+2];
        S00 += px*rx; S01 += px*ry; S02 += px*rz;
        S10 += py*rx; S11 += py*ry; S12 += py*rz;
        S20 += pz*rx; S21 += pz*ry; S22 += pz*rz;
        xs0 += px; xs1 += py; xs2 += pz;
        rs0 += rx; rs1 += ry; rs2 += rz;
    }
    const float inv_a = 1.0f / (float)A_ALIGN;
    float c0 = xs0*inv_a, c1 = xs1*inv_a, c2 = xs2*inv_a;
    float P00 = S00 - c0*rs0, P01 = S01 - c0*rs1, P02 = S02 - c0*rs2;
    float P10 = S10 - c1*rs0, P11 = S11 - c1*rs1, P12 = S12 - c1*rs2;
    float P20 = S20 - c2*rs0, P21 = S21 - c2*rs1, P22 = S22 - c2*rs2;

    float Am[3][3], Vm[3][3];
    Am[0][0] = P00*P00 + P10*P10 + P20*P20;
    Am[0][1] = P00*P01 + P10*P11 + P20*P21;
    Am[0][2] = P00*P02 + P10*P12 + P20*P22;
    Am[1][1] = P01*P01 + P11*P11 + P21*P21;
    Am[1][2] = P01*P02 + P11*P12 + P21*P22;
    Am[2][2] = P02*P02 + P12*P12 + P22*P22;
    Am[1][0]=Am[0][1]; Am[2][0]=Am[0][2]; Am[2][1]=Am[1][2];
    Vm[0][0]=1.f; Vm[0][1]=0.f; Vm[0][2]=0.f;
    Vm[1][0]=0.f; Vm[1][1]=1.f; Vm[1][2]=0.f;
    Vm[2][0]=0.f; Vm[2][1]=0.f; Vm[2][2]=1.f;
#pragma unroll
    for (int sw = 0; sw < 6; ++sw) {
        jrot<0,1,2>(Am, Vm);
        jrot<0,2,1>(Am, Vm);
        jrot<1,2,0>(Am, Vm);
    }

    float l0 = Am[0][0], l1 = Am[1][1], l2 = Am[2][2];
    float v0x=Vm[0][0], v0y=Vm[1][0], v0z=Vm[2][0];
    float v1x=Vm[0][1], v1y=Vm[1][1], v1z=Vm[2][1];
    if (l0 < l1) { float t; t=l0;l0=l1;l1=t;
                   t=v0x;v0x=v1x;v1x=t; t=v0y;v0y=v1y;v1y=t; t=v0z;v0z=v1z;v1z=t; }
    { float v2x=Vm[0][2], v2y=Vm[1][2], v2z=Vm[2][2];
      if (l0 < l2) { float t; t=l0;l0=l2;l2=t;
                     t=v0x;v0x=v2x;v2x=t; t=v0y;v0y=v2y;v2y=t; t=v0z;v0z=v2z;v2z=t; }
      if (l1 < l2) { float t; t=l1;l1=l2;l2=t;
                     t=v1x;v1x=v2x;v2x=t; t=v1y;v1y=v2y;v2y=t; t=v1z;v1z=v2z;v2z=t; }
    }
    float v2x = v0y*v1z - v0z*v1y;
    float v2y = v0z*v1x - v0x*v1z;
    float v2z = v0x*v1y - v0y*v1x;
    float w0x = P00*v0x + P01*v0y + P02*v0z;
    float w0y = P10*v0x + P11*v0y + P12*v0z;
    float w0z = P20*v0x + P21*v0y + P22*v0z;
    float i0 = 1.0f / sqrtf(fmaxf(w0x*w0x+w0y*w0y+w0z*w0z, 1e-30f));
    float u0x=w0x*i0, u0y=w0y*i0, u0z=w0z*i0;
    float w1x = P00*v1x + P01*v1y + P02*v1z;
    float w1y = P10*v1x + P11*v1y + P12*v1z;
    float w1z = P20*v1x + P21*v1y + P22*v1z;
    float d01 = u0x*w1x + u0y*w1y + u0z*w1z;
    w1x -= d01*u0x; w1y -= d01*u0y; w1z -= d01*u0z;
    float i1 = 1.0f / sqrtf(fmaxf(w1x*w1x+w1y*w1y+w1z*w1z, 1e-30f));
    float u1x=w1x*i1, u1y=w1y*i1, u1z=w1z*i1;
    float u2x = u0y*u1z - u0z*u1y;
    float u2y = u0z*u1x - u0x*u1z;
    float u2z = u0x*u1y - u0y*u1x;

    float R00 = u0x*v0x + u1x*v1x + u2x*v2x;
    float R01 = u0x*v0y + u1x*v1y + u2x*v2y;
    float R02 = u0x*v0z + u1x*v1z + u2x*v2z;
    float R10 = u0y*v0x + u1y*v1x + u2y*v2x;
    float R11 = u0y*v0y + u1y*v1y + u2y*v2y;
    float R12 = u0y*v0z + u1y*v1z + u2y*v2z;
    float R20 = u0z*v0x + u1z*v1x + u2z*v2x;
    float R21 = u0z*v0y + u1z*v1y + u2z*v2y;
    float R22 = u0z*v0z + u1z*v1z + u2z*v2z;

    if (!FUSED) {
        float4* w4 = (float4*)(rws + (size_t)b * 12);
        w4[0] = make_float4(R00, R01, R02, R10);
        w4[1] = make_float4(R11, R12, R20, R21);
        w4[2] = make_float4(R22, c0,  c1,  c2);
    } else {
        float* o = out + (size_t)b * (T_TRAIN*3);
#pragma unroll
        for (int t = 0; t < T_TRAIN; ++t) {
            int ti = train_idx[t];
            float x0 = row[ti*3+0]-c0, x1 = row[ti*3+1]-c1, x2 = row[ti*3+2]-c2;
            o[t*3+0] = x0*R00 + x1*R10 + x2*R20;
            o[t*3+1] = x0*R01 + x1*R11 + x2*R21;
            o[t*3+2] = x0*R02 + x1*R12 + x2*R22;
        }
    }
}

// K2: barrier-free wave-streaming apply. One wave = 2 consecutive rows:
// 3 fully-coalesced float4 loads/lane -> own LDS slice (same-wave LDS is
// in-order: no __syncthreads) -> each lane transforms 2 train atoms ->
// float3 (dwordx3) stores; one store instr covers whole 64B lines ->
// no partial-line RMW at any occupancy. 12KB LDS, 32 waves/CU.
__global__ __launch_bounds__(256)
void apply_wave_kernel(const float* __restrict__ traj,
                       const int*   __restrict__ train_idx,
                       const float* __restrict__ rws,
                       float*       __restrict__ out,
                       int B)
{
    __shared__ float lds[4][2 * ROWF];     // per-wave slices, 12288 B

    const int tid = threadIdx.x;
    const int w  = tid >> 6;               // wave in block
    const int l  = tid & 63;               // lane
    const int h  = l >> 5;                 // row within pair
    const int tp = l & 31;                 // train slot base

    const long long pair = (long long)blockIdx.x * 4 + w;
    const long long b    = pair * 2;       // first row of this wave's pair
    if (b >= B) return;                    // wave-uniform
    const long long brow  = b + h;
    const bool      rowok = (brow < B);

    // train slots for this lane (persist in regs)
    int ti0 = train_idx[tp];
    int ti1 = train_idx[tp + 32];

    // ---- stage 2 rows: 192 float4, 3 per lane, fully coalesced ----
    const float4* __restrict__ g4 = (const float4*)traj;
    const long long maxf4 = (long long)B * R4;
    long long fb = b * R4;
    long long i0 = fb + l;        if (i0 >= maxf4) i0 = maxf4 - 1;
    long long i1 = fb + 64 + l;   if (i1 >= maxf4) i1 = maxf4 - 1;
    long long i2 = fb + 128 + l;  if (i2 >= maxf4) i2 = maxf4 - 1;
    float4 v0 = g4[i0];
    float4 v1 = g4[i1];
    float4 v2 = g4[i2];

    // ---- R + centroid for this lane's row (48B, broadcast within half-wave) ----
    const float4* __restrict__ r4 =
        (const float4*)(rws + (rowok ? brow : (long long)(B - 1)) * 12);
    float4 q0 = r4[0], q1 = r4[1], q2 = r4[2];

    float4* s4 = (float4*)lds[w];
    s4[l]       = v0;
    s4[64 + l]  = v1;
    s4[128 + l] = v2;
    // same-wave producer/consumer on own slice: LDS ops are in-order per wave

    const float* __restrict__ rb = &lds[w][h * ROWF];
    float R00=q0.x, R01=q0.y, R02=q0.z, R10=q0.w;
    float R11=q1.x, R12=q1.y, R20=q1.z, R21=q1.w;
    float R22=q2.x, c0=q2.y, c1=q2.z, c2=q2.w;

    if (rowok) {
        {
            float x0 = rb[ti0*3+0]-c0, x1 = rb[ti0*3+1]-c1, x2 = rb[ti0*3+2]-c2;
            float3 y;
            y.x = x0*R00 + x1*R10 + x2*R20;
            y.y = x0*R01 + x1*R11 + x2*R21;
            y.z = x0*R02 + x1*R12 + x2*R22;
            *(float3*)(out + (brow * T_TRAIN + tp) * 3) = y;
        }
        {
            float x0 = rb[ti1*3+0]-c0, x1 = rb[ti1*3+1]-c1, x2 = rb[ti1*3+2]-c2;
            float3 y;
            y.x = x0*R00 + x1*R10 + x2*R20;
            y.y = x0*R01 + x1*R11 + x2*R21;
            y.z = x0*R02 + x1*R12 + x2*R22;
            *(float3*)(out + (brow * T_TRAIN + tp + 32) * 3) = y;
        }
    }
}

extern "C" void kernel_launch(void* const* d_in, const int* in_sizes, int n_in,
                              void* d_out, int out_size, void* d_ws, size_t ws_size,
                              hipStream_t stream)
{
    const float* traj      = (const float*)d_in[0];
    const float* ref_x     = (const float*)d_in[1];
    const int*   align_idx = (const int*)d_in[2];
    const int*   train_idx = (const int*)d_in[3];
    float* out = (float*)d_out;
    int B = in_sizes[0] / (N_ATOMS * 3);

    size_t need = (size_t)12 * (size_t)B * sizeof(float);
    if (ws_size >= need) {
        float* rws = (float*)d_ws;
        int nblk1 = (B + 63) / 64;
        kabsch_rot_kernel<false><<<dim3(nblk1), dim3(64), 0, stream>>>(
            traj, ref_x, align_idx, train_idx, rws, out, B);
        long long pairs = ((long long)B + 1) / 2;
        int nblk2 = (int)((pairs + 3) / 4);
        apply_wave_kernel<<<dim3(nblk2), dim3(256), 0, stream>>>(
            traj, train_idx, rws, out, B);
    } else {
        int nblk1 = (B + 63) / 64;
        kabsch_rot_kernel<true><<<dim3(nblk1), dim3(64), 0, stream>>>(
            traj, ref_x, align_idx, train_idx, nullptr, out, B);
    }
}